// Round 13
// baseline (56.898 us; speedup 1.0000x reference)
//
#include <hip/hip_runtime.h>
#include <math.h>

#define NB 16   // batches
#define NP 900  // predictions (solver columns)
#define NC 91   // classes
#define NT 100  // targets (solver rows)
#define SLOTS 15  // ceil(NP/64) columns owned per lane

// ---------------------------------------------------------------------------
// Kernel A: fused softmax + cost, one 64-lane wave per (b,n) column.
// Grid (16, 225) x 256 thr: blockIdx.x = batch -> XCD-pinned (bid%8 = b%8).
// Ct writes staged through padded LDS -> 16B-contiguous coalesced stores.
// ---------------------------------------------------------------------------
__global__ __launch_bounds__(256) void colcost_kernel(
    const float* __restrict__ cls_pred,   // [B,N,K]
    const float* __restrict__ bb_pred,    // [B,N,4]
    const int*   __restrict__ cls_gt,     // [B,M]
    const float* __restrict__ bb_gt,      // [B,M,4]
    float* __restrict__ Ct)               // [B*M, N]
{
    const int b    = blockIdx.x;
    const int wid  = threadIdx.x >> 6;
    const int lane = threadIdx.x & 63;
    const int n0   = blockIdx.y * 4;         // 4 consecutive columns per block
    const int n    = n0 + wid;               // 225*4 = 900 exact

    __shared__ float probs[4][NC];
    __shared__ float sCt[NT][5];             // +1 pad: conflict-light

    // softmax stats (verified reduce)
    const float* crow = cls_pred + ((size_t)b*NP + n)*NC;
    const float x0 = crow[lane];                                  // lane < 91 always
    const float x1 = (lane + 64 < NC) ? crow[lane + 64] : -INFINITY;
    float mx = fmaxf(x0, x1);
    #pragma unroll
    for (int off = 32; off >= 1; off >>= 1)
        mx = fmaxf(mx, __shfl_xor(mx, off, 64));
    float s = expf(x0 - mx);
    if (lane + 64 < NC) s += expf(x1 - mx);
    #pragma unroll
    for (int off = 32; off >= 1; off >>= 1)
        s += __shfl_xor(s, off, 64);
    const float rinv = 1.0f / s;    // lane-invariant (commutative butterfly)

    probs[wid][lane] = expf(x0 - mx) * rinv;
    if (lane + 64 < NC) probs[wid][lane + 64] = expf(x1 - mx) * rinv;
    __syncthreads();

    // column box (wave-uniform)
    const float4 bp = *reinterpret_cast<const float4*>(bb_pred + ((size_t)b*NP + n)*4);
    const float parea = (bp.z - bp.x) * (bp.w - bp.y);

    #pragma unroll
    for (int h = 0; h < 2; ++h) {
        const int m = lane + 64*h;
        if (m < NT) {
            const int row = b*NT + m;
            const float4 gt = *reinterpret_cast<const float4*>(bb_gt + (size_t)row*4);
            const float garea = (gt.z - gt.x) * (gt.w - gt.y);
            const int   c     = cls_gt[row];

            const float l1 = fabsf(bp.x - gt.x) + fabsf(bp.y - gt.y) +
                             fabsf(bp.z - gt.z) + fabsf(bp.w - gt.w);
            const float xm = fmaxf(bp.x, gt.x);
            const float ym = fmaxf(bp.y, gt.y);
            const float xM = fminf(bp.z, gt.z);
            const float yM = fminf(bp.w, gt.w);
            const float inter = fmaxf(xM - xm, 0.f) * fmaxf(yM - ym, 0.f);
            const float iou = inter / (parea + garea - inter + 1e-6f);
            const float pc  = probs[wid][c];

            sCt[m][wid] = 5.0f*l1 - 2.0f*iou - pc;
        }
    }
    __syncthreads();

    // cooperative tile write: 4 consecutive threads -> 16B contiguous per row
    for (int t = threadIdx.x; t < NT*4; t += 256) {
        const int m = t >> 2, c = t & 3;
        Ct[(size_t)(b*NT + m)*NP + n0 + c] = sCt[m][c];
    }
}

// ---------------------------------------------------------------------------
// JV solver, 256 threads (4 waves) per batch:
//  prologue: 4 waves do row-min/argmin (verified reduce) + LDS atomicMin
//            claim; u/amin/colOwner all in LDS.
//  solve:    wave 0 runs the R9-exact register-machine SAP solver.
// ---------------------------------------------------------------------------
__device__ __forceinline__ int pop_row(unsigned long long& fm0, unsigned long long& fm1)
{
    if (fm0) { const int l = __builtin_ctzll(fm0); fm0 &= fm0 - 1; return l + 1;  }
    if (fm1) { const int l = __builtin_ctzll(fm1); fm1 &= fm1 - 1; return l + 65; }
    return 0;
}

__global__ __launch_bounds__(256) void jv_kernel(
    const float* __restrict__ Ct,        // [B,M,N]
    int* __restrict__ out)               // preds [B,M] then tgts [B,M] (int32)
{
    const int b    = blockIdx.x;
    const int tid  = threadIdx.x;
    const int wid  = tid >> 6;
    const int lane = tid & 63;
    const float* Cb = Ct + (size_t)b*NT*NP;

    __shared__ int   sOwner[NP];     // claimed row per column (INT_MAX = free)
    __shared__ float sU[NT];
    __shared__ int   sAmin[NT];

    for (int j = tid; j < NP; j += 256) sOwner[j] = 0x7FFFFFFF;
    __syncthreads();

    // ---- prologue: row-min + argmin + claim, rows interleaved over 4 waves ----
    for (int m = wid; m < NT; m += 4) {
        const float* cr = Cb + (size_t)m * NP;
        float best = INFINITY; int bj = 0;
        #pragma unroll
        for (int r = 0; r < SLOTS; ++r) {
            const int j = 64*r + lane;
            if ((r < SLOTS-1) || (lane < 4)) {
                const float x = cr[j];
                if (x < best) { best = x; bj = j; }    // ascending j: strict <
            }
        }
        float vmin = best;
        #pragma unroll
        for (int off = 32; off >= 1; off >>= 1)
            vmin = fminf(vmin, __shfl_xor(vmin, off, 64));
        const unsigned long long win = __ballot(best == vmin);
        const int bjAll = __shfl(bj, __builtin_ctzll(win), 64);
        if (lane == 0) {
            sU[m]    = vmin;
            sAmin[m] = bjAll;
            atomicMin(&sOwner[bjAll], m);
        }
    }
    __syncthreads();

    if (wid != 0) return;    // solver is wave 0 only (no further __syncthreads)

    double v[SLOTS], minv[SLOTS];
    float  cw[SLOTS], cnext[SLOTS];
    int    way[SLOTS], p[SLOTS];

    // duals from row reduction: u0 = u[lane+1], u1 = u[lane+65] (1-based rows)
    double u0 = (double)sU[lane];
    double u1 = (lane < NT-64) ? (double)sU[64 + lane] : 0.0;

    // greedy assignment from column claims
    #pragma unroll
    for (int r = 0; r < SLOTS; ++r) {
        v[r] = 0.0; way[r] = 0;
        int o = 0x7FFFFFFF;
        if ((r < SLOTS-1) || (lane < 4)) o = sOwner[64*r + lane];
        p[r] = (o == 0x7FFFFFFF) ? 0 : o + 1;
    }

    // free-row masks (bit l of fm0 = row l+1 free; bit l of fm1 = row l+65)
    const int a0 = sAmin[lane];
    const bool as0 = (sOwner[a0] == lane);
    bool as1 = true;
    if (lane < NT-64) {
        const int a1 = sAmin[64 + lane];
        as1 = (sOwner[a1] == 64 + lane);
    }
    unsigned long long fm0 = __ballot(!as0);
    unsigned long long fm1 = __ballot(!as1 && (lane < NT-64));

    int iCur = pop_row(fm0, fm1);
    if (iCur) {   // prefetch first free row
        const float* cr = Cb + (size_t)(iCur-1)*NP;
        #pragma unroll
        for (int r = 0; r < SLOTS; ++r) {
            int ja = 64*r + lane; if (ja > NP-1) ja = NP-1;
            cnext[r] = cr[ja];
        }
    }

    while (iCur) {
        const int iNext = pop_row(fm0, fm1);

        unsigned usedMask = 0;
        bool it0 = false, it1 = false;
        double Dtot = 0.0;
        #pragma unroll
        for (int r = 0; r < SLOTS; ++r) { minv[r] = INFINITY; cw[r] = cnext[r]; }

        const int i = iCur;
        if (i <= 64) { if (lane == i-1)  it0 = true; }
        else         { if (lane == i-65) it1 = true; }
        double ui0 = (i <= 64) ? __shfl(u0, i-1, 64) : __shfl(u1, i-65, 64);

        if (iNext) {  // prefetch next free row under this phase
            const float* cr = Cb + (size_t)(iNext-1)*NP;
            #pragma unroll
            for (int r = 0; r < SLOTS; ++r) {
                int ja = 64*r + lane; if (ja > NP-1) ja = NP-1;
                cnext[r] = cr[ja];
            }
        }

        int j0 = 0, jfinal;
        while (true) {
            // scan owned columns; update minv/way; local argmin (smallest j)
            double best = INFINITY;
            int    pk   = 0;                      // (p[j] << 10) | j
            #pragma unroll
            for (int r = 0; r < SLOTS; ++r) {
                const int jm1 = 64*r + lane;
                const bool valid = ((r < SLOTS-1) || (lane < 4)) && !((usedMask >> r) & 1u);
                const double cur = valid ? (((double)cw[r] - ui0) - v[r]) : INFINITY;
                if (cur < minv[r]) { minv[r] = cur; way[r] = j0; }
                if (minv[r] < best) { best = minv[r]; pk = (jm1 + 1) | (p[r] << 10); }
            }

            // fp32-key min butterfly; exact fp64 fallback on near-ties
            const float bf = (float)best;
            float vm32 = bf;
            #pragma unroll
            for (int off = 32; off >= 1; off >>= 1)
                vm32 = fminf(vm32, __shfl_xor(vm32, off, 64));
            const unsigned long long cand = __ballot(bf <= vm32 + 1e-3f);
            int winner;
            if (__popcll(cand) == 1) {
                winner = __builtin_ctzll(cand);
            } else {
                double vm = best;
                #pragma unroll
                for (int off = 32; off >= 1; off >>= 1)
                    vm = fmin(vm, __shfl_xor(vm, off, 64));
                winner = __builtin_ctzll(__ballot(best == vm));
            }
            const double delta = __shfl(best, winner, 64);
            pk = __shfl(pk, winner, 64);

            const int j1    = pk & 1023;
            const int pnext = pk >> 10;
            Dtot += delta;
            #pragma unroll
            for (int r = 0; r < SLOTS; ++r) minv[r] -= delta;   // INF stays INF

            // mark j1 used; stamp its entry time into v (net -= later deltas)
            #pragma unroll
            for (int r = 0; r < SLOTS; ++r) {
                if (64*r + lane + 1 == j1) {
                    usedMask |= 1u << r;
                    minv[r] = INFINITY;
                    v[r] += Dtot;
                }
            }

            if (pnext == 0) { jfinal = j1; break; }

            // row pnext enters tree: phase-start u read BEFORE entry stamp
            ui0 = (pnext <= 64) ? __shfl(u0, pnext-1, 64) : __shfl(u1, pnext-65, 64);
            if (pnext <= 64) { if (lane == pnext-1)  { u0 -= Dtot; it0 = true; } }
            else             { if (lane == pnext-65) { u1 -= Dtot; it1 = true; } }

            {   // load row pnext (coalesced, L2-local)
                const float* cr = Cb + (size_t)(pnext-1)*NP;
                #pragma unroll
                for (int r = 0; r < SLOTS; ++r) {
                    int ja = 64*r + lane; if (ja > NP-1) ja = NP-1;
                    cw[r] = cr[ja];
                }
            }
            j0 = j1;
        }

        // augment along the way[] chain
        {
            int jc = jfinal;
            while (jc != 0) {
                int wsel = 0;
                #pragma unroll
                for (int r = 0; r < SLOTS; ++r)
                    if (64*r + lane + 1 == jc) wsel = way[r];
                const int jprev = __shfl(wsel, (jc-1) & 63, 64);
                int newrow;
                if (jprev == 0) newrow = i;
                else {
                    int psel = 0;
                    #pragma unroll
                    for (int r = 0; r < SLOTS; ++r)
                        if (64*r + lane + 1 == jprev) psel = p[r];
                    newrow = __shfl(psel, (jprev-1) & 63, 64);
                }
                #pragma unroll
                for (int r = 0; r < SLOTS; ++r)
                    if (64*r + lane + 1 == jc) p[r] = newrow;
                jc = jprev;
            }
        }

        // phase-end dual writeback
        #pragma unroll
        for (int r = 0; r < SLOTS; ++r)
            if ((usedMask >> r) & 1u) v[r] -= Dtot;
        if (it0) u0 += Dtot;
        if (it1) u1 += Dtot;

        iCur = iNext;
    }

    // emit matches sorted by pred index: rank = #assigned columns with j' < j
    int base = 0;
    #pragma unroll
    for (int r = 0; r < SLOTS; ++r) {
        const unsigned long long mask = __ballot(p[r] != 0);
        if (p[r] != 0) {
            const int rank = base + (int)__popcll(mask & ((1ull << lane) - 1ull));
            out[b*NT + rank]         = 64*r + lane;   // pred index
            out[NB*NT + b*NT + rank] = p[r] - 1;      // target index
        }
        base += (int)__popcll(mask);
    }
}

extern "C" void kernel_launch(void* const* d_in, const int* in_sizes, int n_in,
                              void* d_out, int out_size, void* d_ws, size_t ws_size,
                              hipStream_t stream)
{
    const float* cls_pred = (const float*)d_in[0];
    const float* bb_pred  = (const float*)d_in[1];
    const int*   cls_gt   = (const int*)d_in[2];
    const float* bb_gt    = (const float*)d_in[3];

    float* Ct = (float*)d_ws;   // B*M*N floats = 5.76 MB

    // XCD co-location: blockIdx.x = batch for both kernels.
    colcost_kernel<<<dim3(NB, NP/4), 256, 0, stream>>>(
        cls_pred, bb_pred, cls_gt, bb_gt, Ct);
    jv_kernel<<<NB, 256, 0, stream>>>(Ct, (int*)d_out);
}

// Round 17
// 45.230 us; speedup vs baseline: 1.2580x; 1.2580x over previous
//
#include <hip/hip_runtime.h>
#include <math.h>

#define NB 16   // batches
#define NP 900  // predictions (solver columns)
#define NC 91   // classes
#define NT 100  // targets (solver rows)
#define SLOTS 15  // ceil(NP/64) columns owned per lane

// ---------------------------------------------------------------------------
// Kernel A: fused softmax + cost, one 64-lane wave per (b,n) column.
// Grid (16, 225) x 256 thr: blockIdx.x = batch -> XCD-pinned (bid%8 = b%8).
// Ct writes staged through padded LDS -> 16B-contiguous coalesced stores.
// Side job: init colOwner.
// ---------------------------------------------------------------------------
__global__ __launch_bounds__(256) void colcost_kernel(
    const float* __restrict__ cls_pred,   // [B,N,K]
    const float* __restrict__ bb_pred,    // [B,N,4]
    const int*   __restrict__ cls_gt,     // [B,M]
    const float* __restrict__ bb_gt,      // [B,M,4]
    float* __restrict__ Ct,               // [B*M, N]
    unsigned* __restrict__ colOwner)      // [B, N]
{
    const int b    = blockIdx.x;
    const int wid  = threadIdx.x >> 6;
    const int lane = threadIdx.x & 63;
    const int n0   = blockIdx.y * 4;         // 4 consecutive columns per block
    const int n    = n0 + wid;               // 225*4 = 900 exact

    __shared__ float probs[4][NC];
    __shared__ float sCt[NT][5];             // +1 pad: conflict-light

    if (lane == 0) colOwner[(size_t)b*NP + n] = 0xFFFFFFFFu;

    // softmax stats (verified reduce)
    const float* crow = cls_pred + ((size_t)b*NP + n)*NC;
    const float x0 = crow[lane];                                  // lane < 91 always
    const float x1 = (lane + 64 < NC) ? crow[lane + 64] : -INFINITY;
    float mx = fmaxf(x0, x1);
    #pragma unroll
    for (int off = 32; off >= 1; off >>= 1)
        mx = fmaxf(mx, __shfl_xor(mx, off, 64));
    float s = expf(x0 - mx);
    if (lane + 64 < NC) s += expf(x1 - mx);
    #pragma unroll
    for (int off = 32; off >= 1; off >>= 1)
        s += __shfl_xor(s, off, 64);
    const float rinv = 1.0f / s;    // lane-invariant (commutative butterfly)

    probs[wid][lane] = expf(x0 - mx) * rinv;
    if (lane + 64 < NC) probs[wid][lane + 64] = expf(x1 - mx) * rinv;
    __syncthreads();

    // column box (wave-uniform)
    const float4 bp = *reinterpret_cast<const float4*>(bb_pred + ((size_t)b*NP + n)*4);
    const float parea = (bp.z - bp.x) * (bp.w - bp.y);

    #pragma unroll
    for (int h = 0; h < 2; ++h) {
        const int m = lane + 64*h;
        if (m < NT) {
            const int row = b*NT + m;
            const float4 gt = *reinterpret_cast<const float4*>(bb_gt + (size_t)row*4);
            const float garea = (gt.z - gt.x) * (gt.w - gt.y);
            const int   c     = cls_gt[row];

            const float l1 = fabsf(bp.x - gt.x) + fabsf(bp.y - gt.y) +
                             fabsf(bp.z - gt.z) + fabsf(bp.w - gt.w);
            const float xm = fmaxf(bp.x, gt.x);
            const float ym = fmaxf(bp.y, gt.y);
            const float xM = fminf(bp.z, gt.z);
            const float yM = fminf(bp.w, gt.w);
            const float inter = fmaxf(xM - xm, 0.f) * fmaxf(yM - ym, 0.f);
            const float iou = inter / (parea + garea - inter + 1e-6f);
            const float pc  = probs[wid][c];

            sCt[m][wid] = 5.0f*l1 - 2.0f*iou - pc;
        }
    }
    __syncthreads();

    // cooperative tile write: 4 consecutive threads -> 16B contiguous per row
    for (int t = threadIdx.x; t < NT*4; t += 256) {
        const int m = t >> 2, c = t & 3;
        Ct[(size_t)(b*NT + m)*NP + n0 + c] = sCt[m][c];
    }
}

// ---------------------------------------------------------------------------
// Kernel B: row min + argmin + greedy claim. One wave per (b,m), XCD-pinned.
// ---------------------------------------------------------------------------
__global__ __launch_bounds__(256) void rowmin_claim_kernel(
    const float* __restrict__ Ct,        // [B*M, N]
    float* __restrict__ u_init,          // [B*M]
    int*   __restrict__ amin,            // [B*M]
    unsigned* __restrict__ colOwner)     // [B, N]
{
    const int b    = blockIdx.x;
    const int wid  = threadIdx.x >> 6;
    const int lane = threadIdx.x & 63;
    const int m    = blockIdx.y * 4 + wid;     // 25*4 = 100 exact
    const int row  = b*NT + m;
    const float* cr = Ct + (size_t)row * NP;

    float best = INFINITY; int bj = 0;
    #pragma unroll
    for (int r = 0; r < SLOTS; ++r) {
        const int j = 64*r + lane;
        if ((r < SLOTS-1) || (lane < 4)) {
            const float x = cr[j];
            if (x < best) { best = x; bj = j; }    // ascending j: strict < keeps smallest
        }
    }
    float vmin = best;
    #pragma unroll
    for (int off = 32; off >= 1; off >>= 1)
        vmin = fminf(vmin, __shfl_xor(vmin, off, 64));
    const unsigned long long win = __ballot(best == vmin);
    const int bjAll = __shfl(bj, __builtin_ctzll(win), 64);
    if (lane == 0) {
        u_init[row] = vmin;
        amin[row]   = bjAll;
        atomicMin(&colOwner[(size_t)b*NP + bjAll], (unsigned)m);
    }
}

// ---------------------------------------------------------------------------
// JV solver (verified R12): one 64-lane wave per batch, all state in
// registers. Greedy row-reduction start; shortest-augmenting-path phases for
// free rows only. Lazy fp64 duals; fp32-key butterfly + exact fp64 fallback.
// ---------------------------------------------------------------------------
__device__ __forceinline__ int pop_row(unsigned long long& fm0, unsigned long long& fm1)
{
    if (fm0) { const int l = __builtin_ctzll(fm0); fm0 &= fm0 - 1; return l + 1;  }
    if (fm1) { const int l = __builtin_ctzll(fm1); fm1 &= fm1 - 1; return l + 65; }
    return 0;
}

__global__ __launch_bounds__(64) void jv_kernel(
    const float* __restrict__ Ct,        // [B,M,N]
    const float* __restrict__ u_init,    // [B*M]
    const int*   __restrict__ amin,      // [B*M]
    const unsigned* __restrict__ colOwner, // [B,N]
    int* __restrict__ out)               // preds [B,M] then tgts [B,M] (int32)
{
    const int b    = blockIdx.x;
    const int lane = threadIdx.x;
    const float* Cb = Ct + (size_t)b*NT*NP;

    double v[SLOTS], minv[SLOTS];
    float  cw[SLOTS], cnext[SLOTS];
    int    way[SLOTS], p[SLOTS];

    // duals from row reduction: u0 = u[lane+1], u1 = u[lane+65] (1-based rows)
    double u0 = (double)u_init[b*NT + lane];
    double u1 = (lane < NT-64) ? (double)u_init[b*NT + 64 + lane] : 0.0;

    // greedy assignment from column claims
    #pragma unroll
    for (int r = 0; r < SLOTS; ++r) {
        v[r] = 0.0; way[r] = 0;
        unsigned o = 0xFFFFFFFFu;
        if ((r < SLOTS-1) || (lane < 4)) o = colOwner[(size_t)b*NP + 64*r + lane];
        p[r] = (o == 0xFFFFFFFFu) ? 0 : (int)o + 1;
    }

    // free-row masks (bit l of fm0 = row l+1 free; bit l of fm1 = row l+65)
    const int a0 = amin[b*NT + lane];
    const bool as0 = (colOwner[(size_t)b*NP + a0] == (unsigned)lane);
    bool as1 = true;
    if (lane < NT-64) {
        const int a1 = amin[b*NT + 64 + lane];
        as1 = (colOwner[(size_t)b*NP + a1] == (unsigned)(64 + lane));
    }
    unsigned long long fm0 = __ballot(!as0);
    unsigned long long fm1 = __ballot(!as1 && (lane < NT-64));

    int iCur = pop_row(fm0, fm1);
    if (iCur) {   // prefetch first free row
        const float* cr = Cb + (size_t)(iCur-1)*NP;
        #pragma unroll
        for (int r = 0; r < SLOTS; ++r) {
            int ja = 64*r + lane; if (ja > NP-1) ja = NP-1;
            cnext[r] = cr[ja];
        }
    }

    while (iCur) {
        const int iNext = pop_row(fm0, fm1);

        unsigned usedMask = 0;
        bool it0 = false, it1 = false;
        double Dtot = 0.0;
        #pragma unroll
        for (int r = 0; r < SLOTS; ++r) { minv[r] = INFINITY; cw[r] = cnext[r]; }

        const int i = iCur;
        if (i <= 64) { if (lane == i-1)  it0 = true; }
        else         { if (lane == i-65) it1 = true; }
        double ui0 = (i <= 64) ? __shfl(u0, i-1, 64) : __shfl(u1, i-65, 64);

        if (iNext) {  // prefetch next free row under this phase
            const float* cr = Cb + (size_t)(iNext-1)*NP;
            #pragma unroll
            for (int r = 0; r < SLOTS; ++r) {
                int ja = 64*r + lane; if (ja > NP-1) ja = NP-1;
                cnext[r] = cr[ja];
            }
        }

        int j0 = 0, jfinal;
        while (true) {
            // scan owned columns; update minv/way; local argmin (smallest j)
            double best = INFINITY;
            int    pk   = 0;                      // (p[j] << 10) | j
            #pragma unroll
            for (int r = 0; r < SLOTS; ++r) {
                const int jm1 = 64*r + lane;
                const bool valid = ((r < SLOTS-1) || (lane < 4)) && !((usedMask >> r) & 1u);
                const double cur = valid ? (((double)cw[r] - ui0) - v[r]) : INFINITY;
                if (cur < minv[r]) { minv[r] = cur; way[r] = j0; }
                if (minv[r] < best) { best = minv[r]; pk = (jm1 + 1) | (p[r] << 10); }
            }

            // fp32-key min butterfly; exact fp64 fallback on near-ties.
            const float bf = (float)best;
            float vm32 = bf;
            #pragma unroll
            for (int off = 32; off >= 1; off >>= 1)
                vm32 = fminf(vm32, __shfl_xor(vm32, off, 64));
            const unsigned long long cand = __ballot(bf <= vm32 + 1e-3f);
            int winner;
            if (__popcll(cand) == 1) {
                winner = __builtin_ctzll(cand);
            } else {
                double vm = best;
                #pragma unroll
                for (int off = 32; off >= 1; off >>= 1)
                    vm = fmin(vm, __shfl_xor(vm, off, 64));
                winner = __builtin_ctzll(__ballot(best == vm));
            }
            const double delta = __shfl(best, winner, 64);
            pk = __shfl(pk, winner, 64);

            const int j1    = pk & 1023;
            const int pnext = pk >> 10;
            Dtot += delta;
            #pragma unroll
            for (int r = 0; r < SLOTS; ++r) minv[r] -= delta;   // INF stays INF

            // mark j1 used; stamp its entry time into v (net -= later deltas)
            #pragma unroll
            for (int r = 0; r < SLOTS; ++r) {
                if (64*r + lane + 1 == j1) {
                    usedMask |= 1u << r;
                    minv[r] = INFINITY;
                    v[r] += Dtot;
                }
            }

            if (pnext == 0) { jfinal = j1; break; }

            // row pnext enters tree: phase-start u read BEFORE entry stamp
            ui0 = (pnext <= 64) ? __shfl(u0, pnext-1, 64) : __shfl(u1, pnext-65, 64);
            if (pnext <= 64) { if (lane == pnext-1)  { u0 -= Dtot; it0 = true; } }
            else             { if (lane == pnext-65) { u1 -= Dtot; it1 = true; } }

            {   // load row pnext (coalesced, L2-local)
                const float* cr = Cb + (size_t)(pnext-1)*NP;
                #pragma unroll
                for (int r = 0; r < SLOTS; ++r) {
                    int ja = 64*r + lane; if (ja > NP-1) ja = NP-1;
                    cw[r] = cr[ja];
                }
            }
            j0 = j1;
        }

        // augment along the way[] chain
        {
            int jc = jfinal;
            while (jc != 0) {
                int wsel = 0;
                #pragma unroll
                for (int r = 0; r < SLOTS; ++r)
                    if (64*r + lane + 1 == jc) wsel = way[r];
                const int jprev = __shfl(wsel, (jc-1) & 63, 64);
                int newrow;
                if (jprev == 0) newrow = i;
                else {
                    int psel = 0;
                    #pragma unroll
                    for (int r = 0; r < SLOTS; ++r)
                        if (64*r + lane + 1 == jprev) psel = p[r];
                    newrow = __shfl(psel, (jprev-1) & 63, 64);
                }
                #pragma unroll
                for (int r = 0; r < SLOTS; ++r)
                    if (64*r + lane + 1 == jc) p[r] = newrow;
                jc = jprev;
            }
        }

        // phase-end dual writeback
        #pragma unroll
        for (int r = 0; r < SLOTS; ++r)
            if ((usedMask >> r) & 1u) v[r] -= Dtot;
        if (it0) u0 += Dtot;
        if (it1) u1 += Dtot;

        iCur = iNext;
    }

    // emit matches sorted by pred index: rank = #assigned columns with j' < j
    int base = 0;
    #pragma unroll
    for (int r = 0; r < SLOTS; ++r) {
        const unsigned long long mask = __ballot(p[r] != 0);
        if (p[r] != 0) {
            const int rank = base + (int)__popcll(mask & ((1ull << lane) - 1ull));
            out[b*NT + rank]         = 64*r + lane;   // pred index
            out[NB*NT + b*NT + rank] = p[r] - 1;      // target index
        }
        base += (int)__popcll(mask);
    }
}

extern "C" void kernel_launch(void* const* d_in, const int* in_sizes, int n_in,
                              void* d_out, int out_size, void* d_ws, size_t ws_size,
                              hipStream_t stream)
{
    const float* cls_pred = (const float*)d_in[0];
    const float* bb_pred  = (const float*)d_in[1];
    const int*   cls_gt   = (const int*)d_in[2];
    const float* bb_gt    = (const float*)d_in[3];

    char* base = (char*)d_ws;
    const size_t ctBytes = (size_t)NB*NT*NP*sizeof(float);   // 5.76 MB
    // layout: [Ct][colOwner][u_init][amin]
    float*    Ct       = (float*)base;
    unsigned* colOwner = (unsigned*)(base + ctBytes);
    float*    u_init   = (float*)(base + ctBytes + (size_t)NB*NP*4);
    int*      aminP    = (int*)(base + ctBytes + (size_t)NB*NP*4 + (size_t)NB*NT*4);

    // XCD co-location: blockIdx.x = batch for all three kernels.
    colcost_kernel<<<dim3(NB, NP/4), 256, 0, stream>>>(
        cls_pred, bb_pred, cls_gt, bb_gt, Ct, colOwner);
    rowmin_claim_kernel<<<dim3(NB, NT/4), 256, 0, stream>>>(Ct, u_init, aminP, colOwner);
    jv_kernel<<<NB, 64, 0, stream>>>(Ct, u_init, aminP, colOwner, (int*)d_out);
}